// Round 1
// baseline (1776.373 us; speedup 1.0000x reference)
//
#include <hip/hip_runtime.h>

namespace {
constexpr int T = 2048;
constexpr int B = 4096;
constexpr int H = 32;
constexpr int GPB = 8;  // batch elements (32-lane groups) per 256-thread block

__device__ __forceinline__ float fsigmoid(float x) {
  // 1/(1+e^-x); saturates to 0/1 at extremes, no NaN (rcp(inf)=0)
  return __builtin_amdgcn_rcpf(1.0f + __expf(-x));
}
__device__ __forceinline__ float ftanh_(float x) {
  // 2*sigmoid(2x)-1; saturates to +/-1 at extremes, no NaN
  return 2.0f * __builtin_amdgcn_rcpf(1.0f + __expf(-2.0f * x)) - 1.0f;
}
}  // namespace

__global__ __launch_bounds__(256, 2)
void lstm_fused(const float* __restrict__ x,
                const float* __restrict__ W_ih,
                const float* __restrict__ W_hh,
                const float* __restrict__ b_ih,
                const float* __restrict__ b_hh,
                float* __restrict__ out)
{
  const int j   = threadIdx.x & 31;   // h-index owned by this lane
  const int grp = threadIdx.x >> 5;   // 32-lane group within block
  const int b   = blockIdx.x * GPB + grp;  // batch element

  // ---- per-lane recurrent weights: W_hh rows j, H+j, 2H+j, 3H+j (gate i,f,g,o) ----
  float wi[H], wf[H], wg[H], wo[H];
  {
    const float4* Wv = reinterpret_cast<const float4*>(W_hh);  // [128][8] float4
    #pragma unroll
    for (int q = 0; q < H / 4; ++q) {
      float4 a = Wv[(0 * H + j) * (H / 4) + q];
      wi[4*q+0] = a.x; wi[4*q+1] = a.y; wi[4*q+2] = a.z; wi[4*q+3] = a.w;
      float4 f4 = Wv[(1 * H + j) * (H / 4) + q];
      wf[4*q+0] = f4.x; wf[4*q+1] = f4.y; wf[4*q+2] = f4.z; wf[4*q+3] = f4.w;
      float4 g4 = Wv[(2 * H + j) * (H / 4) + q];
      wg[4*q+0] = g4.x; wg[4*q+1] = g4.y; wg[4*q+2] = g4.z; wg[4*q+3] = g4.w;
      float4 o4 = Wv[(3 * H + j) * (H / 4) + q];
      wo[4*q+0] = o4.x; wo[4*q+1] = o4.y; wo[4*q+2] = o4.z; wo[4*q+3] = o4.w;
    }
  }
  // input weights (I=3) and fused biases for this lane's 4 gate rows
  const float ui0 = W_ih[(0*H+j)*3+0], ui1 = W_ih[(0*H+j)*3+1], ui2 = W_ih[(0*H+j)*3+2];
  const float uf0 = W_ih[(1*H+j)*3+0], uf1 = W_ih[(1*H+j)*3+1], uf2 = W_ih[(1*H+j)*3+2];
  const float ug0 = W_ih[(2*H+j)*3+0], ug1 = W_ih[(2*H+j)*3+1], ug2 = W_ih[(2*H+j)*3+2];
  const float uo0 = W_ih[(3*H+j)*3+0], uo1 = W_ih[(3*H+j)*3+1], uo2 = W_ih[(3*H+j)*3+2];
  const float bi  = b_ih[0*H+j] + b_hh[0*H+j];
  const float bf_ = b_ih[1*H+j] + b_hh[1*H+j];
  const float bg  = b_ih[2*H+j] + b_hh[2*H+j];
  const float bo  = b_ih[3*H+j] + b_hh[3*H+j];

  float h = 0.0f, c = 0.0f;
  const float* xb = x + (size_t)b * T * 3;

  for (int tc = 0; tc < T; tc += 32) {
    // lane j holds x for step tc+j (coalesced chunk load), broadcast by shuffle
    const float* xp = xb + (size_t)(tc + j) * 3;
    float xl0 = xp[0], xl1 = xp[1], xl2 = xp[2];
    #pragma unroll 4
    for (int s = 0; s < 32; ++s) {
      float x0 = __shfl(xl0, s, 32);
      float x1 = __shfl(xl1, s, 32);
      float x2 = __shfl(xl2, s, 32);
      float pi = __builtin_fmaf(x0, ui0, __builtin_fmaf(x1, ui1, __builtin_fmaf(x2, ui2, bi )));
      float pf = __builtin_fmaf(x0, uf0, __builtin_fmaf(x1, uf1, __builtin_fmaf(x2, uf2, bf_)));
      float pg = __builtin_fmaf(x0, ug0, __builtin_fmaf(x1, ug1, __builtin_fmaf(x2, ug2, bg )));
      float po = __builtin_fmaf(x0, uo0, __builtin_fmaf(x1, uo1, __builtin_fmaf(x2, uo2, bo )));
      #pragma unroll
      for (int k = 0; k < H; ++k) {
        float hk = __shfl(h, k, 32);
        pi = __builtin_fmaf(hk, wi[k], pi);
        pf = __builtin_fmaf(hk, wf[k], pf);
        pg = __builtin_fmaf(hk, wg[k], pg);
        po = __builtin_fmaf(hk, wo[k], po);
      }
      float ig = fsigmoid(pi);
      float fg = fsigmoid(pf);
      float gg = ftanh_(pg);
      float og = fsigmoid(po);
      c = __builtin_fmaf(fg, c, ig * gg);
      h = og * ftanh_(c);
    }
  }
  out[b * H + j] = h;
}

extern "C" void kernel_launch(void* const* d_in, const int* in_sizes, int n_in,
                              void* d_out, int out_size, void* d_ws, size_t ws_size,
                              hipStream_t stream) {
  const float* x    = (const float*)d_in[0];
  const float* W_ih = (const float*)d_in[1];
  const float* W_hh = (const float*)d_in[2];
  const float* b_ih = (const float*)d_in[3];
  const float* b_hh = (const float*)d_in[4];
  float* out = (float*)d_out;

  dim3 grid(B / GPB), block(256);
  hipLaunchKernelGGL(lstm_fused, grid, block, 0, stream,
                     x, W_ih, W_hh, b_ih, b_hh, out);
}

// Round 4
// 1589.327 us; speedup vs baseline: 1.1177x; 1.1177x over previous
//
#include <hip/hip_runtime.h>

typedef float v2 __attribute__((ext_vector_type(2)));

#define MEMFENCE() asm volatile("" ::: "memory")

namespace {
constexpr int T = 2048;
constexpr int B = 4096;
constexpr int H = 32;
constexpr int WAVES = 4;   // waves (= batch elements) per 256-thread block
constexpr int CHUNK = 64;  // x timesteps staged per refill

struct WaveLds {
  v2 hdup[H];          // (h_k, h_k) pairs, read as uniform-addr float4 broadcasts
  float4 xbuf[CHUNK];  // (x0,x1,x2,_) per staged step
};
}  // namespace

__global__ __launch_bounds__(256, 4)
void lstm_fused(const float* __restrict__ x,
                const float* __restrict__ W_ih,
                const float* __restrict__ W_hh,
                const float* __restrict__ b_ih,
                const float* __restrict__ b_hh,
                float* __restrict__ out)
{
  __shared__ WaveLds lds[WAVES];
  const int lane = threadIdx.x & 63;
  const int wid  = threadIdx.x >> 6;
  const int j    = lane & 31;
  const bool low = lane < 32;            // low: gates (i,g); high: (f,o)
  const int b    = blockIdx.x * WAVES + wid;
  WaveLds& L = lds[wid];

  const int g0 = (low ? 0 : 1) * H + j;  // i-row (low) / f-row (high)
  const int g1 = (low ? 2 : 3) * H + j;  // g-row (low) / o-row (high)

  // Fold exp2-domain scaling into weights: sigmoid rows * -log2(e),
  // tanh row (g) * -2log2(e). Then act0 = rcp(1+exp2(acc.x)),
  // act1 = fma(rcp(1+exp2(acc.y)), k2, k3).
  const float L2E = 1.442695040888963f;
  const float s0 = -L2E;
  const float s1 = low ? -2.0f * L2E : -L2E;
  const float k2 = low ? 2.0f : 1.0f;
  const float k3 = low ? -1.0f : 0.0f;

  // recurrent weights, packed (gate0, gate1) per k, pre-scaled
  v2 wpk[H];
  {
    const float4* r0 = reinterpret_cast<const float4*>(W_hh + g0 * H);
    const float4* r1 = reinterpret_cast<const float4*>(W_hh + g1 * H);
    #pragma unroll
    for (int q = 0; q < H / 4; ++q) {
      float4 a = r0[q], d = r1[q];
      wpk[4*q+0] = v2{a.x * s0, d.x * s1};
      wpk[4*q+1] = v2{a.y * s0, d.y * s1};
      wpk[4*q+2] = v2{a.z * s0, d.z * s1};
      wpk[4*q+3] = v2{a.w * s0, d.w * s1};
    }
  }
  const v2 u0 = {W_ih[g0*3+0] * s0, W_ih[g1*3+0] * s1};
  const v2 u1 = {W_ih[g0*3+1] * s0, W_ih[g1*3+1] * s1};
  const v2 u2 = {W_ih[g0*3+2] * s0, W_ih[g1*3+2] * s1};
  const v2 bias = {(b_ih[g0] + b_hh[g0]) * s0, (b_ih[g1] + b_hh[g1]) * s1};

  // h starts at 0 (both halves write the same value to the same address)
  L.hdup[j] = v2{0.f, 0.f};
  MEMFENCE();

  float c = 0.f, h = 0.f;
  const float* xb = x + (size_t)b * T * 3;
  const float4* hd4 = reinterpret_cast<const float4*>(L.hdup);

  for (int tcb = 0; tcb < T; tcb += CHUNK) {
    MEMFENCE();
    const float* xp = xb + (size_t)(tcb + lane) * 3;
    L.xbuf[lane] = make_float4(xp[0], xp[1], xp[2], 0.f);
    MEMFENCE();

    #pragma unroll 2
    for (int s = 0; s < CHUNK; ++s) {
      const float4 xv = L.xbuf[s];  // uniform addr -> broadcast
      v2 accA = bias;
      v2 accB = {0.f, 0.f};
      accA = __builtin_elementwise_fma(v2{xv.x, xv.x}, u0, accA);
      accB = __builtin_elementwise_fma(v2{xv.y, xv.y}, u1, accB);
      accA = __builtin_elementwise_fma(v2{xv.z, xv.z}, u2, accA);
      // recurrent: 16 uniform float4 broadcasts -> 32 packed FMAs, 2 chains
      #pragma unroll
      for (int q = 0; q < H / 2; ++q) {
        float4 hh = hd4[q];  // (h_2q, h_2q, h_2q+1, h_2q+1)
        accA = __builtin_elementwise_fma(v2{hh.x, hh.y}, wpk[2*q+0], accA);
        accB = __builtin_elementwise_fma(v2{hh.z, hh.w}, wpk[2*q+1], accB);
      }
      v2 acc = accA + accB;

      // act0 = sigmoid; act1 = tanh (low) / sigmoid (high)
      float e0 = __builtin_amdgcn_exp2f(acc.x);
      float v0 = __builtin_amdgcn_rcpf(1.f + e0);
      float e1 = __builtin_amdgcn_exp2f(acc.y);
      float v1 = __builtin_fmaf(__builtin_amdgcn_rcpf(1.f + e1), k2, k3);

      // exchange with partner half (register-based, no LDS aliasing hazard)
      float p0 = __shfl_xor(v0, 32, 64);
      float p1 = __shfl_xor(v1, 32, 64);
      float sf = low ? p0 : v0;   // sigmoid(f)
      float si = low ? v0 : p0;   // sigmoid(i)
      float so = low ? p1 : v1;   // sigmoid(o)
      float tg = low ? v1 : p1;   // tanh(g)

      c = __builtin_fmaf(sf, c, si * tg);
      float ec = __builtin_amdgcn_exp2f(c * (-2.0f * L2E));
      float th = __builtin_fmaf(__builtin_amdgcn_rcpf(1.f + ec), 2.f, -1.f);
      h = so * th;

      MEMFENCE();
      L.hdup[j] = v2{h, h};  // both halves write same value
      MEMFENCE();
    }
  }

  if (low) out[(size_t)b * H + j] = h;
}

extern "C" void kernel_launch(void* const* d_in, const int* in_sizes, int n_in,
                              void* d_out, int out_size, void* d_ws, size_t ws_size,
                              hipStream_t stream) {
  const float* x    = (const float*)d_in[0];
  const float* W_ih = (const float*)d_in[1];
  const float* W_hh = (const float*)d_in[2];
  const float* b_ih = (const float*)d_in[3];
  const float* b_hh = (const float*)d_in[4];
  float* out = (float*)d_out;

  dim3 grid(B / WAVES), block(256);
  hipLaunchKernelGGL(lstm_fused, grid, block, 0, stream,
                     x, W_ih, W_hh, b_ih, b_hh, out);
}

// Round 5
// 1489.776 us; speedup vs baseline: 1.1924x; 1.0668x over previous
//
#include <hip/hip_runtime.h>

typedef float v2 __attribute__((ext_vector_type(2)));

#define MEMFENCE() asm volatile("" ::: "memory")

namespace {
constexpr int T = 2048;
constexpr int B = 4096;
constexpr int H = 32;
constexpr int WAVES = 4;   // waves (= batch elements) per 256-thread block
constexpr int CHUNK = 64;  // x timesteps staged per refill

struct WaveLds {
  float4 xbuf[CHUNK];  // (x0,x1,x2,_) per staged step
};

// broadcast lane l's value to all lanes as a wave-uniform (SGPR) float
__device__ __forceinline__ float rlane(float v, int l) {
  return __builtin_bit_cast(float,
      __builtin_amdgcn_readlane(__builtin_bit_cast(int, v), l));
}
}  // namespace

__global__ __launch_bounds__(256, 4)
void lstm_fused(const float* __restrict__ x,
                const float* __restrict__ W_ih,
                const float* __restrict__ W_hh,
                const float* __restrict__ b_ih,
                const float* __restrict__ b_hh,
                float* __restrict__ out)
{
  __shared__ WaveLds lds[WAVES];
  const int lane = threadIdx.x & 63;
  const int wid  = threadIdx.x >> 6;
  const int j    = lane & 31;
  const bool low = lane < 32;            // low: gates (i,g); high: (f,o)
  const int b    = blockIdx.x * WAVES + wid;
  WaveLds& L = lds[wid];

  const int g0 = (low ? 0 : 1) * H + j;  // i-row (low) / f-row (high)
  const int g1 = (low ? 2 : 3) * H + j;  // g-row (low) / o-row (high)

  // Fold exp2-domain scaling into weights: sigmoid rows * -log2(e),
  // tanh row (g) * -2log2(e).
  const float L2E = 1.442695040888963f;
  const float s0 = -L2E;
  const float s1 = low ? -2.0f * L2E : -L2E;
  const float k2 = low ? 2.0f : 1.0f;
  const float k3 = low ? -1.0f : 0.0f;

  // recurrent weights, packed (gate0, gate1) per k, pre-scaled
  v2 wpk[H];
  {
    const float4* r0 = reinterpret_cast<const float4*>(W_hh + g0 * H);
    const float4* r1 = reinterpret_cast<const float4*>(W_hh + g1 * H);
    #pragma unroll
    for (int q = 0; q < H / 4; ++q) {
      float4 a = r0[q], d = r1[q];
      wpk[4*q+0] = v2{a.x * s0, d.x * s1};
      wpk[4*q+1] = v2{a.y * s0, d.y * s1};
      wpk[4*q+2] = v2{a.z * s0, d.z * s1};
      wpk[4*q+3] = v2{a.w * s0, d.w * s1};
    }
  }
  const v2 u0 = {W_ih[g0*3+0] * s0, W_ih[g1*3+0] * s1};
  const v2 u1 = {W_ih[g0*3+1] * s0, W_ih[g1*3+1] * s1};
  const v2 u2 = {W_ih[g0*3+2] * s0, W_ih[g1*3+2] * s1};
  const v2 bias = {(b_ih[g0] + b_hh[g0]) * s0, (b_ih[g1] + b_hh[g1]) * s1};

  // State: lane j (low half) holds h_j, c_j. High half's c/h lanes are
  // don't-care (only low half's values are ever read — via readlane 0..31
  // and the final store).
  float c = 0.f, h = 0.f;
  const float* xb = x + (size_t)b * T * 3;

  for (int tcb = 0; tcb < T; tcb += CHUNK) {
    MEMFENCE();
    const float* xp = xb + (size_t)(tcb + lane) * 3;
    L.xbuf[lane] = make_float4(xp[0], xp[1], xp[2], 0.f);
    MEMFENCE();

    #pragma unroll 2
    for (int s = 0; s < CHUNK; ++s) {
      const float4 xv = L.xbuf[s];  // uniform addr -> broadcast (1 DS op)
      v2 accA = __builtin_elementwise_fma(v2{xv.x, xv.x}, u0, bias);
      v2 accB = __builtin_elementwise_fma(v2{xv.y, xv.y}, u1,
                                          v2{xv.z * u2.x, xv.z * u2.y});
      // recurrent: h broadcast via readlane (VALU/SGPR path, no LDS),
      // two independent packed-FMA chains of depth 16
      #pragma unroll
      for (int k = 0; k < H; k += 2) {
        float ha = rlane(h, k);
        float hb = rlane(h, k + 1);
        accA = __builtin_elementwise_fma(v2{ha, ha}, wpk[k],     accA);
        accB = __builtin_elementwise_fma(v2{hb, hb}, wpk[k + 1], accB);
      }
      v2 acc = accA + accB;

      // act0 = sigmoid; act1 = tanh (low) / sigmoid (high)
      float e0 = __builtin_amdgcn_exp2f(acc.x);
      float v0 = __builtin_amdgcn_rcpf(1.f + e0);
      float e1 = __builtin_amdgcn_exp2f(acc.y);
      float v1 = __builtin_fmaf(__builtin_amdgcn_rcpf(1.f + e1), k2, k3);

      // bring the high half's (sigmoid_f, sigmoid_o) to the low half
      float p0 = __shfl_xor(v0, 32, 64);  // low lanes receive sigmoid(f)
      float p1 = __shfl_xor(v1, 32, 64);  // low lanes receive sigmoid(o)

      // low half only: v0=sigmoid(i), v1=tanh(g), p0=sigmoid(f), p1=sigmoid(o)
      // (high half computes garbage here; never consumed)
      c = __builtin_fmaf(p0, c, v0 * v1);
      float ec = __builtin_amdgcn_exp2f(c * (-2.0f * L2E));
      float th = __builtin_fmaf(__builtin_amdgcn_rcpf(1.f + ec), 2.f, -1.f);
      h = p1 * th;
    }
  }

  if (low) out[(size_t)b * H + j] = h;
}

extern "C" void kernel_launch(void* const* d_in, const int* in_sizes, int n_in,
                              void* d_out, int out_size, void* d_ws, size_t ws_size,
                              hipStream_t stream) {
  const float* x    = (const float*)d_in[0];
  const float* W_ih = (const float*)d_in[1];
  const float* W_hh = (const float*)d_in[2];
  const float* b_ih = (const float*)d_in[3];
  const float* b_hh = (const float*)d_in[4];
  float* out = (float*)d_out;

  dim3 grid(B / WAVES), block(256);
  hipLaunchKernelGGL(lstm_fused, grid, block, 0, stream,
                     x, W_ih, W_hh, b_ih, b_hh, out);
}